// Round 9
// baseline (180.189 us; speedup 1.0000x reference)
//
#include <hip/hip_runtime.h>
#include <stdint.h>

#define TT 128
#define BB 4096
#define HH 64
#define BC 16     // batch rows per wave-group
#define HSTR 72   // h LDS row stride (bf16 shorts)

typedef __attribute__((ext_vector_type(8))) short bf16x8;
typedef __attribute__((ext_vector_type(4))) float f32x4;

static __device__ __forceinline__ short f2bf(float f) {  // RNE, one-time W convert
  uint32_t u = __builtin_bit_cast(uint32_t, f);
  u += 0x7fffu + ((u >> 16) & 1u);
  return (short)(u >> 16);
}
static __device__ __forceinline__ uint32_t cvtpk(float a, float b) {
  uint32_t r;
  asm("v_cvt_pk_bf16_f32 %0, %1, %2" : "=v"(r) : "v"(a), "v"(b));
  return r;  // lo16 = bf16(a), hi16 = bf16(b)
}
static __device__ __forceinline__ float rcpf(float x) { return __builtin_amdgcn_rcpf(x); }
static __device__ __forceinline__ float sigm(float x) { return rcpf(1.0f + __expf(-x)); }
static __device__ __forceinline__ float tanhf_fast(float x) {
  float e = __expf(2.0f * x);
  return 1.0f - 2.0f * rcpf(e + 1.0f);
}

// Single wave per block: the whole 16-batch GRU recurrence lives in one wave.
// No s_barrier anywhere. h is exchanged through a 2.3KB LDS tile; ordering is
// guaranteed by in-order issue + lgkmcnt within the wave.
__global__ __launch_bounds__(64, 1) void gru_wave(
    const float* __restrict__ Hseq, const float* __restrict__ W_ih,
    const float* __restrict__ W_hh, const float* __restrict__ b_ih,
    const float* __restrict__ b_hh, const float* __restrict__ W_out,
    const float* __restrict__ b_out, float* __restrict__ out) {
  __shared__ __align__(16) short hsh[BC][HSTR];  // bf16 h, single buffer

  const int l   = threadIdx.x;   // 0..63
  const int llo = l & 15;        // batch col (B/D) and W row (A)
  const int lhi = l >> 4;        // 0..3
  const int k0  = lhi * 8;
  const int bbase = blockIdx.x * BC;

  // ---- all W fragments persistent: 12 row-chunks x 2 k-halves, both matrices ----
  // chunks 0-3: r-gate rows 0..63; 4-7: z rows 64..127; 8-11: n rows 128..191
  bf16x8 wih[12][2], whh[12][2];
#pragma unroll
  for (int c = 0; c < 12; ++c) {
    const int grow = 16 * c + llo;
#pragma unroll
    for (int hf = 0; hf < 2; ++hf) {
      const float* p = &W_ih[grow * 64 + hf * 32 + k0];
      const float* q = &W_hh[grow * 64 + hf * 32 + k0];
      bf16x8 a, b;
#pragma unroll
      for (int i = 0; i < 8; ++i) { a[i] = f2bf(p[i]); b[i] = f2bf(q[i]); }
      wih[c][hf] = a;
      whh[c][hf] = b;
    }
  }

  // ---- bias fragments per chunk q: row j = 16q + 4lhi + r ----
  f32x4 bR[4], bZ[4], bXN[4], bHN[4];
#pragma unroll
  for (int q = 0; q < 4; ++q) {
#pragma unroll
    for (int r = 0; r < 4; ++r) {
      const int j = 16 * q + 4 * lhi + r;
      bR[q][r]  = b_ih[j] + b_hh[j];
      bZ[q][r]  = b_ih[64 + j] + b_hh[64 + j];
      bXN[q][r] = b_ih[128 + j];
      bHN[q][r] = b_hh[128 + j];
    }
  }

  // zero h LDS (h0 = 0): 16*72 shorts = 576 ints, 9 per lane
  {
    int* p = (int*)hsh;
#pragma unroll
    for (int i = 0; i < 9; ++i) p[l + 64 * i] = 0;
  }

  const float* xroot = Hseq + (size_t)(bbase + llo) * HH + k0;

  // ---- prologue: c-tiles for t=0 from x[0]; prefetch xqA=x[1], xqB=x[2] ----
  f32x4 cR[4], cZ[4], cXN[4];
  {
    const f32x4* pv = (const f32x4*)xroot;
    f32x4 q0 = pv[0], q1 = pv[1], q2 = pv[8], q3 = pv[9];
    union { uint32_t u[4]; bf16x8 v; } x0, x1;
    x0.u[0] = cvtpk(q0[0], q0[1]); x0.u[1] = cvtpk(q0[2], q0[3]);
    x0.u[2] = cvtpk(q1[0], q1[1]); x0.u[3] = cvtpk(q1[2], q1[3]);
    x1.u[0] = cvtpk(q2[0], q2[1]); x1.u[1] = cvtpk(q2[2], q2[3]);
    x1.u[2] = cvtpk(q3[0], q3[1]); x1.u[3] = cvtpk(q3[2], q3[3]);
#pragma unroll
    for (int q = 0; q < 4; ++q) {
      cR[q]  = __builtin_amdgcn_mfma_f32_16x16x32_bf16(wih[q][0], x0.v, bR[q], 0, 0, 0);
      cR[q]  = __builtin_amdgcn_mfma_f32_16x16x32_bf16(wih[q][1], x1.v, cR[q], 0, 0, 0);
      cZ[q]  = __builtin_amdgcn_mfma_f32_16x16x32_bf16(wih[4 + q][0], x0.v, bZ[q], 0, 0, 0);
      cZ[q]  = __builtin_amdgcn_mfma_f32_16x16x32_bf16(wih[4 + q][1], x1.v, cZ[q], 0, 0, 0);
      cXN[q] = __builtin_amdgcn_mfma_f32_16x16x32_bf16(wih[8 + q][0], x0.v, bXN[q], 0, 0, 0);
      cXN[q] = __builtin_amdgcn_mfma_f32_16x16x32_bf16(wih[8 + q][1], x1.v, cXN[q], 0, 0, 0);
    }
  }
  f32x4 xqA0, xqA1, xqA2, xqA3, xqB0, xqB1, xqB2, xqB3;
  {
    const f32x4* pa = (const f32x4*)(xroot + (size_t)1 * BB * HH);
    xqA0 = pa[0]; xqA1 = pa[1]; xqA2 = pa[8]; xqA3 = pa[9];
    const f32x4* pb = (const f32x4*)(xroot + (size_t)2 * BB * HH);
    xqB0 = pb[0]; xqB1 = pb[1]; xqB2 = pb[8]; xqB3 = pb[9];
  }

  f32x4 hfp[4] = {{0,0,0,0},{0,0,0,0},{0,0,0,0},{0,0,0,0}};  // fp32 h carry

  // One step. Consumes cR/cZ/cXN (built last step from x[t]); rebuilds them
  // from XQ (= x[t+1], loaded 2 steps ago); refills XQ <- x[TN].
#define STEP(XQ0, XQ1, XQ2, XQ3, TN)                                          \
  {                                                                           \
    asm volatile("s_waitcnt lgkmcnt(0)" ::: "memory");                        \
    const bf16x8 hb0 = *(const bf16x8*)&hsh[llo][k0];                         \
    const bf16x8 hb1 = *(const bf16x8*)&hsh[llo][k0 + 32];                    \
    union { uint32_t u[4]; bf16x8 v; } x0, x1;                                \
    x0.u[0] = cvtpk(XQ0[0], XQ0[1]); x0.u[1] = cvtpk(XQ0[2], XQ0[3]);         \
    x0.u[2] = cvtpk(XQ1[0], XQ1[1]); x0.u[3] = cvtpk(XQ1[2], XQ1[3]);         \
    x1.u[0] = cvtpk(XQ2[0], XQ2[1]); x1.u[1] = cvtpk(XQ2[2], XQ2[3]);         \
    x1.u[2] = cvtpk(XQ3[0], XQ3[1]); x1.u[3] = cvtpk(XQ3[2], XQ3[3]);         \
    {                                                                         \
      const int tn = (TN) < TT ? (TN) : (TT - 1);                             \
      const f32x4* pv = (const f32x4*)(xroot + (size_t)tn * BB * HH);         \
      XQ0 = pv[0]; XQ1 = pv[1]; XQ2 = pv[8]; XQ3 = pv[9];                     \
    }                                                                         \
    f32x4 aR[4], aZ[4], aHN[4];                                               \
    _Pragma("unroll")                                                         \
    for (int q = 0; q < 4; ++q) {                                             \
      aR[q]  = __builtin_amdgcn_mfma_f32_16x16x32_bf16(whh[q][0], hb0, cR[q], 0, 0, 0);      \
      aR[q]  = __builtin_amdgcn_mfma_f32_16x16x32_bf16(whh[q][1], hb1, aR[q], 0, 0, 0);      \
      aZ[q]  = __builtin_amdgcn_mfma_f32_16x16x32_bf16(whh[4 + q][0], hb0, cZ[q], 0, 0, 0);  \
      aZ[q]  = __builtin_amdgcn_mfma_f32_16x16x32_bf16(whh[4 + q][1], hb1, aZ[q], 0, 0, 0);  \
      aHN[q] = __builtin_amdgcn_mfma_f32_16x16x32_bf16(whh[8 + q][0], hb0, bHN[q], 0, 0, 0); \
      aHN[q] = __builtin_amdgcn_mfma_f32_16x16x32_bf16(whh[8 + q][1], hb1, aHN[q], 0, 0, 0); \
    }                                                                         \
    /* rebuild cR,cZ for next step (this step's copies already consumed) */   \
    _Pragma("unroll")                                                         \
    for (int q = 0; q < 4; ++q) {                                             \
      cR[q] = __builtin_amdgcn_mfma_f32_16x16x32_bf16(wih[q][0], x0.v, bR[q], 0, 0, 0);      \
      cR[q] = __builtin_amdgcn_mfma_f32_16x16x32_bf16(wih[q][1], x1.v, cR[q], 0, 0, 0);      \
      cZ[q] = __builtin_amdgcn_mfma_f32_16x16x32_bf16(wih[4 + q][0], x0.v, bZ[q], 0, 0, 0);  \
      cZ[q] = __builtin_amdgcn_mfma_f32_16x16x32_bf16(wih[4 + q][1], x1.v, cZ[q], 0, 0, 0);  \
    }                                                                         \
    /* gates + carry update (fp32) */                                         \
    _Pragma("unroll")                                                         \
    for (int q = 0; q < 4; ++q) {                                             \
      _Pragma("unroll")                                                       \
      for (int r = 0; r < 4; ++r) {                                           \
        const float rr = sigm(aR[q][r]);                                      \
        const float zz = sigm(aZ[q][r]);                                      \
        const float nn = tanhf_fast(cXN[q][r] + rr * aHN[q][r]);              \
        hfp[q][r] = nn + zz * (hfp[q][r] - nn);                               \
      }                                                                       \
    }                                                                         \
    /* rebuild cXN (was needed by gates above) */                             \
    _Pragma("unroll")                                                         \
    for (int q = 0; q < 4; ++q) {                                             \
      cXN[q] = __builtin_amdgcn_mfma_f32_16x16x32_bf16(wih[8 + q][0], x0.v, bXN[q], 0, 0, 0); \
      cXN[q] = __builtin_amdgcn_mfma_f32_16x16x32_bf16(wih[8 + q][1], x1.v, cXN[q], 0, 0, 0); \
    }                                                                         \
    /* publish h (in-wave LDS, no barrier) */                                 \
    _Pragma("unroll")                                                         \
    for (int q = 0; q < 4; ++q) {                                             \
      uint2 pk;                                                               \
      pk.x = cvtpk(hfp[q][0], hfp[q][1]);                                     \
      pk.y = cvtpk(hfp[q][2], hfp[q][3]);                                     \
      *(uint2*)&hsh[llo][16 * q + 4 * lhi] = pk;                              \
    }                                                                         \
  }

  for (int t = 0; t < TT; t += 2) {
    STEP(xqA0, xqA1, xqA2, xqA3, t + 3);
    STEP(xqB0, xqB1, xqB2, xqB3, t + 4);
  }
#undef STEP

  // ---- head: out[b] = h_last[b,:] . W_out + b_out (shuffle reduce) ----
  float part = 0.f;
#pragma unroll
  for (int q = 0; q < 4; ++q)
#pragma unroll
    for (int r = 0; r < 4; ++r) part += hfp[q][r] * W_out[16 * q + 4 * lhi + r];
  part += __shfl_xor(part, 16);
  part += __shfl_xor(part, 32);
  if (lhi == 0) out[bbase + llo] = part + b_out[0];
}

extern "C" void kernel_launch(void* const* d_in, const int* in_sizes, int n_in,
                              void* d_out, int out_size, void* d_ws, size_t ws_size,
                              hipStream_t stream) {
  (void)in_sizes; (void)n_in; (void)d_ws; (void)ws_size; (void)out_size;
  const float* Hseq  = (const float*)d_in[0];
  const float* W_ih  = (const float*)d_in[1];
  const float* W_hh  = (const float*)d_in[2];
  const float* b_ih  = (const float*)d_in[3];
  const float* b_hh  = (const float*)d_in[4];
  const float* W_out = (const float*)d_in[5];
  const float* b_out = (const float*)d_in[6];
  float* out = (float*)d_out;
  gru_wave<<<BB / BC, 64, 0, stream>>>(Hseq, W_ih, W_hh, b_ih, b_hh, W_out, b_out, out);
}

// Round 10
// 70.722 us; speedup vs baseline: 2.5478x; 2.5478x over previous
//
#include <hip/hip_runtime.h>
#include <stdint.h>

#define TT 128
#define BB 4096
#define HH 64
#define BC 16      // batch rows per block
#define XSTR 196   // xg LDS row stride (floats); 49 dwords -> conflict-light
#define HSTR 72    // h LDS row stride (bf16 shorts): 144B rows, 16B aligned

typedef __attribute__((ext_vector_type(8))) short bf16x8;
typedef __attribute__((ext_vector_type(4))) float f32x4;

static __device__ __forceinline__ short f2bf(float f) {  // RNE, one-time W convert
  uint32_t u = __builtin_bit_cast(uint32_t, f);
  u += 0x7fffu + ((u >> 16) & 1u);
  return (short)(u >> 16);
}
static __device__ __forceinline__ uint32_t cvtpk(float a, float b) {
  uint32_t r;
  asm("v_cvt_pk_bf16_f32 %0, %1, %2" : "=v"(r) : "v"(a), "v"(b));
  return r;  // lo16 = bf16(a), hi16 = bf16(b)
}
static __device__ __forceinline__ float rcpf(float x) { return __builtin_amdgcn_rcpf(x); }

// lgkm-only barrier: LDS ops drain, global prefetch loads stay in flight.
static __device__ __forceinline__ void block_sync_lds() {
  asm volatile("" ::: "memory");
  asm volatile("s_waitcnt lgkmcnt(0)" ::: "memory");
  __builtin_amdgcn_s_barrier();
  asm volatile("" ::: "memory");
}

#define MFMA __builtin_amdgcn_mfma_f32_16x16x32_bf16

__global__ __launch_bounds__(512) void gru_fused(
    const float* __restrict__ Hseq, const float* __restrict__ W_ih,
    const float* __restrict__ W_hh, const float* __restrict__ b_ih,
    const float* __restrict__ b_hh, const float* __restrict__ W_out,
    const float* __restrict__ b_out, float* __restrict__ out) {
  __shared__ __align__(16) short hsh[2][BC][HSTR];   // bf16 h state, double buffered
  __shared__ __align__(16) float xgsh[2][BC][XSTR];  // fp32 x-side gate preacts
  __shared__ float psum[4][BC];

  const int tid = threadIdx.x;
  const int w   = tid >> 6;     // 0..7; 0-3 consumers (recurrence), 4-7 producers (x GEMM)
  const int gw  = w & 3;        // gate-row chunk: j in [16gw, 16gw+16)
  const bool cons = (w < 4);
  const int l   = tid & 63;
  const int llo = l & 15;       // batch col (B/D frags) or gate row (A frag)
  const int lhi = l >> 4;
  const int k0  = lhi * 8;
  const int bbase = blockIdx.x * BC;

  // zero h buffer 0 (h0 = 0)
  for (int i = tid; i < BC * HSTR; i += 512) ((short*)hsh[0])[i] = 0;

  bf16x8 wa[3][2];                       // consumer: W_hh frags; producer: W_ih frags
  f32x4 biasHN = {0, 0, 0, 0};           // consumer only
  f32x4 biasPR = {0, 0, 0, 0}, biasPZ = {0, 0, 0, 0}, biasPN = {0, 0, 0, 0};  // producer

  if (cons) {
#pragma unroll
    for (int c = 0; c < 3; ++c) {
      const int grow = 16 * gw + 64 * c + llo;
#pragma unroll
      for (int hf = 0; hf < 2; ++hf) {
        const float* q = &W_hh[grow * 64 + hf * 32 + k0];
        bf16x8 b;
#pragma unroll
        for (int i = 0; i < 8; ++i) b[i] = f2bf(q[i]);
        wa[c][hf] = b;
      }
    }
#pragma unroll
    for (int r = 0; r < 4; ++r) biasHN[r] = b_hh[128 + 16 * gw + 4 * lhi + r];
  } else {
#pragma unroll
    for (int c = 0; c < 3; ++c) {
      const int grow = 16 * gw + 64 * c + llo;
#pragma unroll
      for (int hf = 0; hf < 2; ++hf) {
        const float* p = &W_ih[grow * 64 + hf * 32 + k0];
        bf16x8 a;
#pragma unroll
        for (int i = 0; i < 8; ++i) a[i] = f2bf(p[i]);
        wa[c][hf] = a;
      }
    }
#pragma unroll
    for (int r = 0; r < 4; ++r) {
      const int j = 16 * gw + 4 * lhi + r;
      biasPR[r] = b_ih[j] + b_hh[j];
      biasPZ[r] = b_ih[64 + j] + b_hh[64 + j];
      biasPN[r] = b_ih[128 + j];
    }
  }

  const float* xroot = Hseq + (size_t)(bbase + llo) * HH + k0;  // per-lane t=0 base
  f32x4 xqA0, xqA1, xqA2, xqA3, xqB0, xqB1, xqB2, xqB3;  // producer 2-deep prefetch
  f32x4 hfp = {0.f, 0.f, 0.f, 0.f};  // consumer fp32 h (batch llo, 4 j's)

  // producer pre-step: xg[0] into buffer 0, then prefetch x[1] and x[2]
  if (!cons) {
    const f32x4* pv = (const f32x4*)xroot;  // x[0]
    f32x4 q0 = pv[0], q1 = pv[1], q2 = pv[8], q3 = pv[9];
    union { uint32_t u[4]; bf16x8 v; } c0, c1;
    c0.u[0] = cvtpk(q0[0], q0[1]); c0.u[1] = cvtpk(q0[2], q0[3]);
    c0.u[2] = cvtpk(q1[0], q1[1]); c0.u[3] = cvtpk(q1[2], q1[3]);
    c1.u[0] = cvtpk(q2[0], q2[1]); c1.u[1] = cvtpk(q2[2], q2[3]);
    c1.u[2] = cvtpk(q3[0], q3[1]); c1.u[3] = cvtpk(q3[2], q3[3]);
    f32x4 cR = biasPR, cZ = biasPZ, cN = biasPN;
    cR = MFMA(wa[0][0], c0.v, cR, 0, 0, 0);
    cR = MFMA(wa[0][1], c1.v, cR, 0, 0, 0);
    cZ = MFMA(wa[1][0], c0.v, cZ, 0, 0, 0);
    cZ = MFMA(wa[1][1], c1.v, cZ, 0, 0, 0);
    cN = MFMA(wa[2][0], c0.v, cN, 0, 0, 0);
    cN = MFMA(wa[2][1], c1.v, cN, 0, 0, 0);
    *(f32x4*)&xgsh[0][llo][16 * gw + 4 * lhi]       = cR;
    *(f32x4*)&xgsh[0][llo][64 + 16 * gw + 4 * lhi]  = cZ;
    *(f32x4*)&xgsh[0][llo][128 + 16 * gw + 4 * lhi] = cN;
    const f32x4* pa = (const f32x4*)(xroot + (size_t)1 * BB * HH);  // x[1]
    xqA0 = pa[0]; xqA1 = pa[1]; xqA2 = pa[8]; xqA3 = pa[9];
    const f32x4* pb = (const f32x4*)(xroot + (size_t)2 * BB * HH);  // x[2]
    xqB0 = pb[0]; xqB1 = pb[1]; xqB2 = pb[8]; xqB3 = pb[9];
  }
  block_sync_lds();

  // Consumer step: critical path. aR chain starts first; 5-trans gate algebra:
  //   u=e^-aR, t=e^-aZ, rr=1/(1+u), c=clamp(xn+rr*hn), s=e^(2c)
  //   h' = (t*(s-1) + h*(s+1)) / ((s+1)*(1+t))    [== n + z*(h-n), NaN-free]
#define CSTEP(RB, WB)                                                         \
  {                                                                           \
    __builtin_amdgcn_s_setprio(1);                                            \
    const bf16x8 hb0 = *(const bf16x8*)&hsh[RB][llo][k0];                     \
    const bf16x8 hb1 = *(const bf16x8*)&hsh[RB][llo][k0 + 32];                \
    f32x4 aR = *(const f32x4*)&xgsh[RB][llo][16 * gw + 4 * lhi];              \
    aR = MFMA(wa[0][0], hb0, aR, 0, 0, 0);                                    \
    aR = MFMA(wa[0][1], hb1, aR, 0, 0, 0);                                    \
    f32x4 aZ  = *(const f32x4*)&xgsh[RB][llo][64 + 16 * gw + 4 * lhi];        \
    f32x4 aXN = *(const f32x4*)&xgsh[RB][llo][128 + 16 * gw + 4 * lhi];       \
    aZ  = MFMA(wa[1][0], hb0, aZ, 0, 0, 0);                                   \
    aZ  = MFMA(wa[1][1], hb1, aZ, 0, 0, 0);                                   \
    f32x4 aHN = MFMA(wa[2][0], hb0, biasHN, 0, 0, 0);                         \
    aHN = MFMA(wa[2][1], hb1, aHN, 0, 0, 0);                                  \
    _Pragma("unroll")                                                         \
    for (int r = 0; r < 4; ++r) {                                             \
      const float u  = __expf(-aR[r]);                                        \
      const float az = fminf(30.f, fmaxf(-30.f, aZ[r]));                      \
      const float t  = __expf(-az);                                           \
      const float rr = rcpf(1.0f + u);                                        \
      float c = aXN[r] + rr * aHN[r];                                         \
      c = fminf(15.f, fmaxf(-15.f, c));                                       \
      const float s   = __expf(2.0f * c);                                     \
      const float qq  = s + 1.0f;                                             \
      const float num = t * (s - 1.0f) + hfp[r] * qq;                         \
      const float den = qq * (1.0f + t);                                      \
      hfp[r] = num * rcpf(den);                                               \
    }                                                                         \
    uint2 pk;                                                                 \
    pk.x = cvtpk(hfp[0], hfp[1]);                                             \
    pk.y = cvtpk(hfp[2], hfp[3]);                                             \
    *(uint2*)&hsh[WB][llo][16 * gw + 4 * lhi] = pk;                           \
    __builtin_amdgcn_s_setprio(0);                                            \
  }

  // Producer step: build xg[next] into xgsh[OB] from XQ regs; refill XQ<-x[TN].
#define PSTEP(OB, XQ0, XQ1, XQ2, XQ3, TN)                                     \
  {                                                                           \
    union { uint32_t u[4]; bf16x8 v; } c0, c1;                                \
    c0.u[0] = cvtpk(XQ0[0], XQ0[1]); c0.u[1] = cvtpk(XQ0[2], XQ0[3]);         \
    c0.u[2] = cvtpk(XQ1[0], XQ1[1]); c0.u[3] = cvtpk(XQ1[2], XQ1[3]);         \
    c1.u[0] = cvtpk(XQ2[0], XQ2[1]); c1.u[1] = cvtpk(XQ2[2], XQ2[3]);         \
    c1.u[2] = cvtpk(XQ3[0], XQ3[1]); c1.u[3] = cvtpk(XQ3[2], XQ3[3]);         \
    {                                                                         \
      const int tn = (TN) < TT ? (TN) : (TT - 1);                             \
      const f32x4* pv = (const f32x4*)(xroot + (size_t)tn * BB * HH);         \
      XQ0 = pv[0]; XQ1 = pv[1]; XQ2 = pv[8]; XQ3 = pv[9];                     \
    }                                                                         \
    f32x4 cR = biasPR, cZ = biasPZ, cN = biasPN;                              \
    cR = MFMA(wa[0][0], c0.v, cR, 0, 0, 0);                                   \
    cR = MFMA(wa[0][1], c1.v, cR, 0, 0, 0);                                   \
    cZ = MFMA(wa[1][0], c0.v, cZ, 0, 0, 0);                                   \
    cZ = MFMA(wa[1][1], c1.v, cZ, 0, 0, 0);                                   \
    cN = MFMA(wa[2][0], c0.v, cN, 0, 0, 0);                                   \
    cN = MFMA(wa[2][1], c1.v, cN, 0, 0, 0);                                   \
    *(f32x4*)&xgsh[OB][llo][16 * gw + 4 * lhi]       = cR;                    \
    *(f32x4*)&xgsh[OB][llo][64 + 16 * gw + 4 * lhi]  = cZ;                    \
    *(f32x4*)&xgsh[OB][llo][128 + 16 * gw + 4 * lhi] = cN;                    \
  }

  for (int t = 0; t < TT; t += 2) {
    if (cons) { CSTEP(0, 1) } else { PSTEP(1, xqA0, xqA1, xqA2, xqA3, t + 3) }
    block_sync_lds();
    if (cons) { CSTEP(1, 0) } else { PSTEP(0, xqB0, xqB1, xqB2, xqB3, t + 4) }
    block_sync_lds();
  }
#undef CSTEP
#undef PSTEP

  // ---- head: out[b] = h_last[b,:] . W_out + b_out ----
  if (cons) {
    float part = 0.f;
#pragma unroll
    for (int r = 0; r < 4; ++r) part += hfp[r] * W_out[16 * gw + 4 * lhi + r];
    part += __shfl_xor(part, 16);
    part += __shfl_xor(part, 32);
    if (lhi == 0) psum[gw][llo] = part;
  }
  block_sync_lds();
  if (tid < BC)
    out[bbase + tid] = psum[0][tid] + psum[1][tid] + psum[2][tid] + psum[3][tid] + b_out[0];
}

extern "C" void kernel_launch(void* const* d_in, const int* in_sizes, int n_in,
                              void* d_out, int out_size, void* d_ws, size_t ws_size,
                              hipStream_t stream) {
  (void)in_sizes; (void)n_in; (void)d_ws; (void)ws_size; (void)out_size;
  const float* Hseq  = (const float*)d_in[0];
  const float* W_ih  = (const float*)d_in[1];
  const float* W_hh  = (const float*)d_in[2];
  const float* b_ih  = (const float*)d_in[3];
  const float* b_hh  = (const float*)d_in[4];
  const float* W_out = (const float*)d_in[5];
  const float* b_out = (const float*)d_in[6];
  float* out = (float*)d_out;
  gru_fused<<<BB / BC, 512, 0, stream>>>(Hseq, W_ih, W_hh, b_ih, b_hh, W_out, b_out, out);
}

// Round 11
// 69.720 us; speedup vs baseline: 2.5845x; 1.0144x over previous
//
#include <hip/hip_runtime.h>
#include <stdint.h>

#define TT 128
#define BB 4096
#define HH 64
#define BC 16      // batch rows per block
#define XSTR 196   // xg LDS row stride (floats); 49 dwords, 16B aligned
#define HSTR 72    // h LDS row stride (bf16 shorts): 144B rows, 16B aligned

typedef __attribute__((ext_vector_type(8))) short bf16x8;
typedef __attribute__((ext_vector_type(4))) float f32x4;

static __device__ __forceinline__ short f2bf(float f) {  // RNE, one-time W convert
  uint32_t u = __builtin_bit_cast(uint32_t, f);
  u += 0x7fffu + ((u >> 16) & 1u);
  return (short)(u >> 16);
}
static __device__ __forceinline__ uint32_t cvtpk(float a, float b) {
  uint32_t r;
  asm("v_cvt_pk_bf16_f32 %0, %1, %2" : "=v"(r) : "v"(a), "v"(b));
  return r;  // lo16 = bf16(a), hi16 = bf16(b)
}
static __device__ __forceinline__ float rcpf(float x) { return __builtin_amdgcn_rcpf(x); }
static __device__ __forceinline__ float sigm(float x) { return rcpf(1.0f + __expf(-x)); }
static __device__ __forceinline__ float tanhf_fast(float x) {
  float e = __expf(2.0f * x);
  return 1.0f - 2.0f * rcpf(e + 1.0f);
}

// lgkm-only barrier: LDS ops drain, global prefetch loads stay in flight.
static __device__ __forceinline__ void block_sync_lds() {
  asm volatile("" ::: "memory");
  asm volatile("s_waitcnt lgkmcnt(0)" ::: "memory");
  __builtin_amdgcn_s_barrier();
  asm volatile("" ::: "memory");
}

#define MFMA __builtin_amdgcn_mfma_f32_16x16x32_bf16

__global__ __launch_bounds__(512) void gru_fused(
    const float* __restrict__ Hseq, const float* __restrict__ W_ih,
    const float* __restrict__ W_hh, const float* __restrict__ b_ih,
    const float* __restrict__ b_hh, const float* __restrict__ W_out,
    const float* __restrict__ b_out, float* __restrict__ out) {
  __shared__ __align__(16) short hsh[2][BC][HSTR];   // bf16 h state, double buffered
  __shared__ __align__(16) float xgsh[4][BC][XSTR];  // fp32 x-side preacts, 4-ring (prod 2 ahead)
  __shared__ float psum[4][BC];

  const int tid = threadIdx.x;
  const int w   = tid >> 6;     // 0..7; 0-3 consumers (recurrence), 4-7 producers (x GEMM)
  const int gw  = w & 3;        // gate-row chunk: j in [16gw, 16gw+16)
  const bool cons = (w < 4);
  const int l   = tid & 63;
  const int llo = l & 15;       // batch col (B/D frags) or gate row (A frag)
  const int lhi = l >> 4;
  const int k0  = lhi * 8;
  const int bbase = blockIdx.x * BC;
  const f32x4 fz = {0.f, 0.f, 0.f, 0.f};

  // zero h buffer 0 (h0 = 0)
  for (int i = tid; i < BC * HSTR; i += 512) ((short*)hsh[0])[i] = 0;

  bf16x8 wa[3][2];                       // consumer: W_hh frags; producer: W_ih frags
  f32x4 biasHN = fz;                     // consumer only
  f32x4 biasPR = fz, biasPZ = fz, biasPN = fz;  // producer only

  if (cons) {
#pragma unroll
    for (int c = 0; c < 3; ++c) {
      const int grow = 16 * gw + 64 * c + llo;
#pragma unroll
      for (int hf = 0; hf < 2; ++hf) {
        const float* q = &W_hh[grow * 64 + hf * 32 + k0];
        bf16x8 b;
#pragma unroll
        for (int i = 0; i < 8; ++i) b[i] = f2bf(q[i]);
        wa[c][hf] = b;
      }
    }
#pragma unroll
    for (int r = 0; r < 4; ++r) biasHN[r] = b_hh[128 + 16 * gw + 4 * lhi + r];
  } else {
#pragma unroll
    for (int c = 0; c < 3; ++c) {
      const int grow = 16 * gw + 64 * c + llo;
#pragma unroll
      for (int hf = 0; hf < 2; ++hf) {
        const float* p = &W_ih[grow * 64 + hf * 32 + k0];
        bf16x8 a;
#pragma unroll
        for (int i = 0; i < 8; ++i) a[i] = f2bf(p[i]);
        wa[c][hf] = a;
      }
    }
#pragma unroll
    for (int r = 0; r < 4; ++r) {
      const int j = 16 * gw + 4 * lhi + r;
      biasPR[r] = b_ih[j] + b_hh[j];
      biasPZ[r] = b_ih[64 + j] + b_hh[64 + j];
      biasPN[r] = b_ih[128 + j];
    }
  }

  const float* xroot = Hseq + (size_t)(bbase + llo) * HH + k0;  // per-lane t=0 base
  f32x4 xqA0, xqA1, xqA2, xqA3, xqB0, xqB1, xqB2, xqB3;  // producer 2-deep x prefetch
  f32x4 hfp = fz;                                        // consumer fp32 h
  f32x4 xgE0, xgE1, xgE2, xgO0, xgO1, xgO2;              // consumer xg reg sets (even/odd t)

  // Producer prologue: build xg[0]->buf0, xg[1]->buf1; prefetch x[2](A), x[3](B).
  if (!cons) {
#pragma unroll
    for (int s = 0; s < 2; ++s) {
      const f32x4* pv = (const f32x4*)(xroot + (size_t)s * BB * HH);
      f32x4 q0 = pv[0], q1 = pv[1], q2 = pv[8], q3 = pv[9];
      union { uint32_t u[4]; bf16x8 v; } c0, c1;
      c0.u[0] = cvtpk(q0[0], q0[1]); c0.u[1] = cvtpk(q0[2], q0[3]);
      c0.u[2] = cvtpk(q1[0], q1[1]); c0.u[3] = cvtpk(q1[2], q1[3]);
      c1.u[0] = cvtpk(q2[0], q2[1]); c1.u[1] = cvtpk(q2[2], q2[3]);
      c1.u[2] = cvtpk(q3[0], q3[1]); c1.u[3] = cvtpk(q3[2], q3[3]);
      f32x4 cR = biasPR, cZ = biasPZ, cN = biasPN;
      cR = MFMA(wa[0][0], c0.v, cR, 0, 0, 0);
      cR = MFMA(wa[0][1], c1.v, cR, 0, 0, 0);
      cZ = MFMA(wa[1][0], c0.v, cZ, 0, 0, 0);
      cZ = MFMA(wa[1][1], c1.v, cZ, 0, 0, 0);
      cN = MFMA(wa[2][0], c0.v, cN, 0, 0, 0);
      cN = MFMA(wa[2][1], c1.v, cN, 0, 0, 0);
      *(f32x4*)&xgsh[s][llo][16 * gw + 4 * lhi]       = cR;
      *(f32x4*)&xgsh[s][llo][64 + 16 * gw + 4 * lhi]  = cZ;
      *(f32x4*)&xgsh[s][llo][128 + 16 * gw + 4 * lhi] = cN;
    }
    const f32x4* pa = (const f32x4*)(xroot + (size_t)2 * BB * HH);
    xqA0 = pa[0]; xqA1 = pa[1]; xqA2 = pa[8]; xqA3 = pa[9];
    const f32x4* pb = (const f32x4*)(xroot + (size_t)3 * BB * HH);
    xqB0 = pb[0]; xqB1 = pb[1]; xqB2 = pb[8]; xqB3 = pb[9];
  }
  block_sync_lds();

  // Consumer pre-read: xg[0] -> even reg set (C-inputs for step 0).
  if (cons) {
    xgE0 = *(const f32x4*)&xgsh[0][llo][16 * gw + 4 * lhi];
    xgE1 = *(const f32x4*)&xgsh[0][llo][64 + 16 * gw + 4 * lhi];
    xgE2 = *(const f32x4*)&xgsh[0][llo][128 + 16 * gw + 4 * lhi];
  }

  // Consumer step (phase-literal): h reads + prefetch next xg into regs; the
  // aR MFMA pair is split (independent halves + vector add) to cut one MFMA
  // dep-latency off the head of the gate chain. aXN (XGC2) is pure register.
#define CSTEP(RBH, WBH, NB, XGC0, XGC1, XGC2, XGN0, XGN1, XGN2)               \
  {                                                                           \
    const bf16x8 hb0 = *(const bf16x8*)&hsh[RBH][llo][k0];                    \
    const bf16x8 hb1 = *(const bf16x8*)&hsh[RBH][llo][k0 + 32];               \
    XGN0 = *(const f32x4*)&xgsh[NB][llo][16 * gw + 4 * lhi];                  \
    XGN1 = *(const f32x4*)&xgsh[NB][llo][64 + 16 * gw + 4 * lhi];             \
    XGN2 = *(const f32x4*)&xgsh[NB][llo][128 + 16 * gw + 4 * lhi];            \
    f32x4 aR0 = MFMA(wa[0][0], hb0, XGC0, 0, 0, 0);                           \
    f32x4 aR1 = MFMA(wa[0][1], hb1, fz, 0, 0, 0);                             \
    f32x4 aZ  = MFMA(wa[1][0], hb0, XGC1, 0, 0, 0);                           \
    aZ        = MFMA(wa[1][1], hb1, aZ, 0, 0, 0);                             \
    f32x4 aHN = MFMA(wa[2][0], hb0, biasHN, 0, 0, 0);                         \
    aHN       = MFMA(wa[2][1], hb1, aHN, 0, 0, 0);                            \
    const f32x4 aR = aR0 + aR1;                                               \
    _Pragma("unroll")                                                         \
    for (int r = 0; r < 4; ++r) {                                             \
      const float rr = sigm(aR[r]);                                           \
      const float zz = sigm(aZ[r]);                                           \
      const float nn = tanhf_fast(XGC2[r] + rr * aHN[r]);                     \
      hfp[r] = nn + zz * (hfp[r] - nn);                                       \
    }                                                                         \
    uint2 pk;                                                                 \
    pk.x = cvtpk(hfp[0], hfp[1]);                                             \
    pk.y = cvtpk(hfp[2], hfp[3]);                                             \
    *(uint2*)&hsh[WBH][llo][16 * gw + 4 * lhi] = pk;                          \
  }

  // Producer step: build xg[t+2] -> buf WRBUF from XQ (= x[t+2]); refill XQ<-x[TN].
#define PSTEP(WRBUF, XQ0, XQ1, XQ2, XQ3, TN)                                  \
  {                                                                           \
    union { uint32_t u[4]; bf16x8 v; } c0, c1;                                \
    c0.u[0] = cvtpk(XQ0[0], XQ0[1]); c0.u[1] = cvtpk(XQ0[2], XQ0[3]);         \
    c0.u[2] = cvtpk(XQ1[0], XQ1[1]); c0.u[3] = cvtpk(XQ1[2], XQ1[3]);         \
    c1.u[0] = cvtpk(XQ2[0], XQ2[1]); c1.u[1] = cvtpk(XQ2[2], XQ2[3]);         \
    c1.u[2] = cvtpk(XQ3[0], XQ3[1]); c1.u[3] = cvtpk(XQ3[2], XQ3[3]);         \
    {                                                                         \
      const int tn = (TN) < TT ? (TN) : (TT - 1);                             \
      const f32x4* pv = (const f32x4*)(xroot + (size_t)tn * BB * HH);         \
      XQ0 = pv[0]; XQ1 = pv[1]; XQ2 = pv[8]; XQ3 = pv[9];                     \
    }                                                                         \
    f32x4 cR = biasPR, cZ = biasPZ, cN = biasPN;                              \
    cR = MFMA(wa[0][0], c0.v, cR, 0, 0, 0);                                   \
    cR = MFMA(wa[0][1], c1.v, cR, 0, 0, 0);                                   \
    cZ = MFMA(wa[1][0], c0.v, cZ, 0, 0, 0);                                   \
    cZ = MFMA(wa[1][1], c1.v, cZ, 0, 0, 0);                                   \
    cN = MFMA(wa[2][0], c0.v, cN, 0, 0, 0);                                   \
    cN = MFMA(wa[2][1], c1.v, cN, 0, 0, 0);                                   \
    *(f32x4*)&xgsh[WRBUF][llo][16 * gw + 4 * lhi]       = cR;                 \
    *(f32x4*)&xgsh[WRBUF][llo][64 + 16 * gw + 4 * lhi]  = cZ;                 \
    *(f32x4*)&xgsh[WRBUF][llo][128 + 16 * gw + 4 * lhi] = cN;                 \
  }

  for (int t = 0; t < TT; t += 4) {
    // t+0: h rd buf0, xg cur=E, prefetch buf1->O; producer writes buf2 from A
    if (cons) { CSTEP(0, 1, 1, xgE0, xgE1, xgE2, xgO0, xgO1, xgO2) }
    else      { PSTEP(2, xqA0, xqA1, xqA2, xqA3, t + 4) }
    block_sync_lds();
    // t+1: h rd buf1, cur=O, prefetch buf2->E; producer writes buf3 from B
    if (cons) { CSTEP(1, 0, 2, xgO0, xgO1, xgO2, xgE0, xgE1, xgE2) }
    else      { PSTEP(3, xqB0, xqB1, xqB2, xqB3, t + 5) }
    block_sync_lds();
    // t+2: h rd buf0, cur=E, prefetch buf3->O; producer writes buf0 from A
    if (cons) { CSTEP(0, 1, 3, xgE0, xgE1, xgE2, xgO0, xgO1, xgO2) }
    else      { PSTEP(0, xqA0, xqA1, xqA2, xqA3, t + 6) }
    block_sync_lds();
    // t+3: h rd buf1, cur=O, prefetch buf0->E; producer writes buf1 from B
    if (cons) { CSTEP(1, 0, 0, xgO0, xgO1, xgO2, xgE0, xgE1, xgE2) }
    else      { PSTEP(1, xqB0, xqB1, xqB2, xqB3, t + 7) }
    block_sync_lds();
  }
#undef CSTEP
#undef PSTEP

  // ---- head: out[b] = h_last[b,:] . W_out + b_out ----
  if (cons) {
    float part = 0.f;
#pragma unroll
    for (int r = 0; r < 4; ++r) part += hfp[r] * W_out[16 * gw + 4 * lhi + r];
    part += __shfl_xor(part, 16);
    part += __shfl_xor(part, 32);
    if (lhi == 0) psum[gw][llo] = part;
  }
  block_sync_lds();
  if (tid < BC)
    out[bbase + tid] = psum[0][tid] + psum[1][tid] + psum[2][tid] + psum[3][tid] + b_out[0];
}

extern "C" void kernel_launch(void* const* d_in, const int* in_sizes, int n_in,
                              void* d_out, int out_size, void* d_ws, size_t ws_size,
                              hipStream_t stream) {
  (void)in_sizes; (void)n_in; (void)d_ws; (void)ws_size; (void)out_size;
  const float* Hseq  = (const float*)d_in[0];
  const float* W_ih  = (const float*)d_in[1];
  const float* W_hh  = (const float*)d_in[2];
  const float* b_ih  = (const float*)d_in[3];
  const float* b_hh  = (const float*)d_in[4];
  const float* W_out = (const float*)d_in[5];
  const float* b_out = (const float*)d_in[6];
  float* out = (float*)d_out;
  gru_fused<<<BB / BC, 512, 0, stream>>>(Hseq, W_ih, W_hh, b_ih, b_hh, W_out, b_out, out);
}